// Round 14
// baseline (175.637 us; speedup 1.0000x reference)
//
#include <hip/hip_runtime.h>
#include <math.h>

typedef __attribute__((ext_vector_type(4))) float f32x4;
typedef __attribute__((ext_vector_type(8))) short s16x8;
typedef __attribute__((ext_vector_type(4))) short s16x4;
typedef __attribute__((ext_vector_type(2))) int i32x2;
typedef __attribute__((ext_vector_type(4))) int i32x4;

// small-GEMM tile
#define BM 32
#define BN 256
#define BK 64
#define LDS_TILE ((BM + BN) * BK)

// big-GEMM tile (int8)
#define BM2 128
#define BN2 256
#define BK2 128
#define KFULL 8192
#define ZSPLIT 4
#define KQ (KFULL / ZSPLIT)
#define ABYTES (BM2 * BK2)
#define BBYTES (BN2 * BK2)
#define BUFB (ABYTES + BBYTES)

#define SHS 2048.0f
#define S16C (64.0f / (254.0f * 2048.0f))
#define INVSHS (1.0f / 2048.0f)

__device__ __forceinline__ unsigned short f2bf(float f) {
  unsigned int u = __float_as_uint(f);
  u += 0x7fffu + ((u >> 16) & 1u);
  return (unsigned short)(u >> 16);
}
__device__ __forceinline__ float bf2f(unsigned short h) {
  unsigned int u = ((unsigned int)h) << 16;
  return __uint_as_float(u);
}
__device__ __forceinline__ int rne_i(float x) {
  return __float_as_int(x + 12582912.0f) - 0x4B400000;
}
__device__ __forceinline__ int q_hs(float v) {
  int q = rne_i(v * SHS);
  return q < -127 ? -127 : (q > 127 ? 127 : q);
}
__device__ __forceinline__ void gload16(const void* g, void* l) {
  __builtin_amdgcn_global_load_lds(
      (const __attribute__((address_space(1))) void*)g,
      (__attribute__((address_space(3))) void*)l, 16, 0, 0);
}

// ---------------- small GEMM (bf16 MFMA): h1 = (x @ W1 + b1)^T ----------------
__device__ __forceinline__ void gemm_small3(int bx, unsigned short* ldsb,
                                            const float* __restrict__ A,
                                            const float* __restrict__ Bf,
                                            unsigned short* __restrict__ outp,
                                            const float* __restrict__ bias,
                                            int M, int N, int K) {
  const int tid = threadIdx.x;
  const int m0 = (bx & (M / BM - 1)) * BM;
  const int n0 = (bx / (M / BM)) * BN;
  const int sr = tid >> 3;
  const int sc = (tid & 7) * 8;

  float a_t[8];
  f32x4 b_f[8][2];

  auto stage_load = [&](int k0) {
#pragma unroll
    for (int j = 0; j < 8; ++j)
      a_t[j] = A[(size_t)(k0 + sc + j) * M + m0 + sr];
#pragma unroll
    for (int it = 0; it < 8; ++it) {
      int n = n0 + it * 32 + sr;
      const float* p = Bf + (size_t)n * K + k0 + sc;
      b_f[it][0] = *(const f32x4*)(p);
      b_f[it][1] = *(const f32x4*)(p + 4);
    }
  };

  auto stage_write = [&](int buf) {
    unsigned short* L = ldsb + buf * LDS_TILE;
    {
      s16x8 v;
#pragma unroll
      for (int j = 0; j < 8; ++j) v[j] = (short)f2bf(a_t[j]);
      int idx = (sr * BK + sc) ^ ((sr & 7) << 3);
      *(s16x8*)(L + idx) = v;
    }
#pragma unroll
    for (int it = 0; it < 8; ++it) {
      int r = it * 32 + sr;
      s16x8 w;
#pragma unroll
      for (int j = 0; j < 8; ++j)
        w[j] = (short)f2bf(j < 4 ? b_f[it][0][j] : b_f[it][1][j - 4]);
      int idx = BM * BK + ((r * BK + sc) ^ ((r & 7) << 3));
      *(s16x8*)(L + idx) = w;
    }
  };

  const int lane = tid & 63;
  const int wv = tid >> 6;
  const int g = lane >> 4, lr = lane & 15;

  int aidx[2][2], bidx[4][2];
#pragma unroll
  for (int m = 0; m < 2; ++m)
#pragma unroll
    for (int ks = 0; ks < 2; ++ks) {
      int r = m * 16 + lr;
      aidx[m][ks] = (r * BK + ks * 32 + g * 8) ^ ((r & 7) << 3);
    }
#pragma unroll
  for (int n = 0; n < 4; ++n)
#pragma unroll
    for (int ks = 0; ks < 2; ++ks) {
      int r = wv * 64 + n * 16 + lr;
      bidx[n][ks] = BM * BK + ((r * BK + ks * 32 + g * 8) ^ ((r & 7) << 3));
    }

  f32x4 acc[2][4];
#pragma unroll
  for (int m = 0; m < 2; ++m)
#pragma unroll
    for (int n = 0; n < 4; ++n) {
      f32x4 z = {0.f, 0.f, 0.f, 0.f};
      acc[m][n] = z;
    }

  auto compute = [&](int buf) {
    const unsigned short* L = ldsb + buf * LDS_TILE;
    s16x8 af[2][2], bfr[4][2];
#pragma unroll
    for (int m = 0; m < 2; ++m)
#pragma unroll
      for (int ks = 0; ks < 2; ++ks) af[m][ks] = *(const s16x8*)(L + aidx[m][ks]);
#pragma unroll
    for (int n = 0; n < 4; ++n)
#pragma unroll
      for (int ks = 0; ks < 2; ++ks) bfr[n][ks] = *(const s16x8*)(L + bidx[n][ks]);
#pragma unroll
    for (int m = 0; m < 2; ++m)
#pragma unroll
      for (int n = 0; n < 4; ++n)
#pragma unroll
        for (int ks = 0; ks < 2; ++ks)
          acc[m][n] = __builtin_amdgcn_mfma_f32_16x16x32_bf16(af[m][ks], bfr[n][ks],
                                                              acc[m][n], 0, 0, 0);
  };

  stage_load(0);
  stage_write(0);
  __syncthreads();
  int cur = 0;
  const int nt = K / BK;
  for (int t = 0; t < nt; ++t) {
    if (t + 1 < nt) stage_load((t + 1) * BK);
    compute(cur);
    if (t + 1 < nt) {
      stage_write(cur ^ 1);
      __syncthreads();
      cur ^= 1;
    }
  }

#pragma unroll
  for (int m = 0; m < 2; ++m)
#pragma unroll
    for (int n = 0; n < 4; ++n) {
      int col = n0 + wv * 64 + n * 16 + lr;
#pragma unroll
      for (int r = 0; r < 4; ++r) {
        int row = m0 + m * 16 + g * 4 + r;
        outp[(size_t)row * N + col] = f2bf(acc[m][n][r] + bias[row]);
      }
    }
}

// ---------------- prep (fused, R12): gemm3 blocks [0,256) + adjconv [256,4352) ----------------
__global__ __launch_bounds__(256) void prep(const float* __restrict__ adj,
                                            const float* __restrict__ x,
                                            const float* __restrict__ W1,
                                            const float* __restrict__ b1,
                                            char* __restrict__ adjq,
                                            float* __restrict__ dinv,
                                            unsigned short* __restrict__ h1,
                                            int* __restrict__ colsum1,
                                            int* __restrict__ colsum2) {
  __shared__ unsigned short lds[2 * LDS_TILE];
  int bx = blockIdx.x;
  if (bx < 256) {
    gemm_small3(bx, lds, W1, x, h1, b1, 256, 8192, 512);
    return;
  }
  bx -= 256;
  const int tid = threadIdx.x;
  if (bx == 0) {
    colsum1[tid] = 0;
    colsum2[tid] = 0;
  }
  float* smf = (float*)lds;
  float psum[2];
#pragma unroll
  for (int rr = 0; rr < 2; ++rr) {
    int row = bx * 2 + rr;
    const float* src = adj + (size_t)row * 8192;
    char* dst = adjq + (size_t)row * 8192;
    float s = 0.f;
    for (int c = tid * 8; c < 8192; c += 2048) {
      f32x4 v0 = __builtin_nontemporal_load((const f32x4*)(src + c));
      f32x4 v1 = __builtin_nontemporal_load((const f32x4*)(src + c + 4));
      s += v0[0] + v0[1] + v0[2] + v0[3] + v1[0] + v1[1] + v1[2] + v1[3];
      i32x2 o;
      o[0] = (rne_i((v0[0] - 0.5f) * 254.f) & 0xff) |
             ((rne_i((v0[1] - 0.5f) * 254.f) & 0xff) << 8) |
             ((rne_i((v0[2] - 0.5f) * 254.f) & 0xff) << 16) |
             (rne_i((v0[3] - 0.5f) * 254.f) << 24);
      o[1] = (rne_i((v1[0] - 0.5f) * 254.f) & 0xff) |
             ((rne_i((v1[1] - 0.5f) * 254.f) & 0xff) << 8) |
             ((rne_i((v1[2] - 0.5f) * 254.f) & 0xff) << 16) |
             (rne_i((v1[3] - 0.5f) * 254.f) << 24);
      *(i32x2*)(dst + c) = o;
    }
    psum[rr] = s;
  }
#pragma unroll
  for (int rr = 0; rr < 2; ++rr) {
    float s = psum[rr];
#pragma unroll
    for (int off = 32; off > 0; off >>= 1) s += __shfl_down(s, off, 64);
    if ((tid & 63) == 0) smf[rr * 4 + (tid >> 6)] = s;
  }
  __syncthreads();
  if (tid < 2) {
    float tot = smf[tid * 4] + smf[tid * 4 + 1] + smf[tid * 4 + 2] + smf[tid * 4 + 3];
    dinv[bx * 2 + tid] = rsqrtf(tot + 1.0f);
  }
}

// ---------------- scale_tr: hq1[h][k]=q(h1*dinv[k]) + hq1n[k][h] + colsum1 ----------------
__global__ __launch_bounds__(256) void scale_tr(const unsigned short* __restrict__ h1,
                                                const float* __restrict__ dinv,
                                                char* __restrict__ hq1,
                                                char* __restrict__ hq1n,
                                                int* __restrict__ colsum1) {
  __shared__ char Tq[64][80];
  __shared__ int colA[64];
  int nt_ = blockIdx.x >> 2, ht = blockIdx.x & 3;
  int n0 = nt_ * 64, h0 = ht * 64;
  const int tid = threadIdx.x;
  const int c8 = (tid & 7) * 8;
  if (tid < 64) colA[tid] = 0;
  __syncthreads();
  f32x4 d0 = *(const f32x4*)(dinv + n0 + c8);
  f32x4 d1 = *(const f32x4*)(dinv + n0 + c8 + 4);
#pragma unroll
  for (int it = 0; it < 2; ++it) {
    int hh = (tid >> 3) + it * 32;
    s16x8 v = *(const s16x8*)(h1 + (size_t)(h0 + hh) * 8192 + n0 + c8);
    unsigned int lo = 0, hi = 0;
    int ssum = 0;
#pragma unroll
    for (int j = 0; j < 8; ++j) {
      float dv = (j < 4) ? d0[j] : d1[j - 4];
      int q = q_hs(bf2f((unsigned short)v[j]) * dv);
      Tq[c8 + j][hh] = (char)q;
      ssum += q;
      if (j < 4) lo |= ((unsigned int)(q & 0xff)) << (8 * j);
      else       hi |= ((unsigned int)(q & 0xff)) << (8 * (j - 4));
    }
    i32x2 o;
    o[0] = (int)lo;
    o[1] = (int)hi;
    *(i32x2*)(hq1 + (size_t)(h0 + hh) * 8192 + n0 + c8) = o;
    ssum += __shfl_xor(ssum, 1, 64);
    ssum += __shfl_xor(ssum, 2, 64);
    ssum += __shfl_xor(ssum, 4, 64);
    if ((tid & 7) == 0) atomicAdd(&colA[hh], ssum);
  }
  __syncthreads();
  int node = tid >> 2, h16 = (tid & 3) * 16;
  i32x4 vv = *(const i32x4*)(&Tq[node][h16]);
  *(i32x4*)(hq1n + (size_t)(n0 + node) * 256 + h0 + h16) = vv;
  if (tid < 64) atomicAdd(&colsum1[h0 + tid], colA[tid]);
}

// ---------------- big GEMM int8 (split-K=4): P16[z] = (adjq_c @ Bq^T + 32) >> 6 ----------------
__global__ __launch_bounds__(512) void gemm_big(const char* __restrict__ A,
                                                const char* __restrict__ B,
                                                short* __restrict__ P16) {
  __shared__ char lds[3 * BUFB];
  const int tid = threadIdx.x;
  const int mt = blockIdx.x & 63;
  const int z = blockIdx.x >> 6;
  const int m0 = mt * BM2;

  const int trow = tid >> 3;
  const int srcgr = (tid & 7) ^ (trow & 7);

  const char* Asrc[2];
#pragma unroll
  for (int j = 0; j < 2; ++j)
    Asrc[j] = A + (size_t)(m0 + j * 64 + trow) * KFULL + (size_t)z * KQ + srcgr * 16;
  const char* Bsrc[4];
#pragma unroll
  for (int j = 0; j < 4; ++j)
    Bsrc[j] = B + (size_t)(j * 64 + trow) * KFULL + (size_t)z * KQ + srcgr * 16;

  auto stage = [&](int buf, int t) {
    char* L = lds + buf * BUFB;
#pragma unroll
    for (int j = 0; j < 2; ++j)
      gload16(Asrc[j] + (size_t)t * BK2, L + (j * 512 + tid) * 16);
#pragma unroll
    for (int j = 0; j < 4; ++j)
      gload16(Bsrc[j] + (size_t)t * BK2, L + ABYTES + (j * 512 + tid) * 16);
  };

  const int w = tid >> 6, l = tid & 63;
  const int wr = w >> 2, wc = w & 3;
  const int g = l >> 4, lr = l & 15;
  int aoff[4][2], boff[4][2];
#pragma unroll
  for (int m = 0; m < 4; ++m)
#pragma unroll
    for (int ks = 0; ks < 2; ++ks) {
      int r = wr * 64 + m * 16 + lr;
      aoff[m][ks] = r * BK2 + (((ks * 4 + g) ^ (r & 7)) * 16);
    }
#pragma unroll
  for (int n = 0; n < 4; ++n)
#pragma unroll
    for (int ks = 0; ks < 2; ++ks) {
      int r = wc * 64 + n * 16 + lr;
      boff[n][ks] = ABYTES + r * BK2 + (((ks * 4 + g) ^ (r & 7)) * 16);
    }

  i32x4 acc[4][4];
#pragma unroll
  for (int m = 0; m < 4; ++m)
#pragma unroll
    for (int n = 0; n < 4; ++n) {
      i32x4 zz = {0, 0, 0, 0};
      acc[m][n] = zz;
    }

  stage(0, 0);
  stage(1, 1);

  const int nt = KQ / BK2;  // 16
  for (int t = 0; t < nt; ++t) {
    int cur = t % 3;
    if (t + 1 < nt) asm volatile("s_waitcnt vmcnt(6)" ::: "memory");
    else            asm volatile("s_waitcnt vmcnt(0)" ::: "memory");
    asm volatile("s_barrier" ::: "memory");
    __builtin_amdgcn_sched_barrier(0);

    const char* L = lds + cur * BUFB;
    i32x4 af[4][2], bfr[4][2];
#pragma unroll
    for (int m = 0; m < 4; ++m)
#pragma unroll
      for (int ks = 0; ks < 2; ++ks) af[m][ks] = *(const i32x4*)(L + aoff[m][ks]);
#pragma unroll
    for (int n = 0; n < 4; ++n)
#pragma unroll
      for (int ks = 0; ks < 2; ++ks) bfr[n][ks] = *(const i32x4*)(L + boff[n][ks]);

    if (t + 2 < nt) stage((t + 2) % 3, t + 2);

    __builtin_amdgcn_s_setprio(1);
#pragma unroll
    for (int m = 0; m < 4; ++m)
#pragma unroll
      for (int n = 0; n < 4; ++n)
#pragma unroll
        for (int ks = 0; ks < 2; ++ks)
          acc[m][n] = __builtin_amdgcn_mfma_i32_16x16x64_i8(af[m][ks], bfr[n][ks],
                                                            acc[m][n], 0, 0, 0);
    __builtin_amdgcn_s_setprio(0);
  }

  __syncthreads();
  unsigned short* Tp = (unsigned short*)lds;
#pragma unroll
  for (int m = 0; m < 4; ++m)
#pragma unroll
    for (int n = 0; n < 4; ++n) {
      int cl = wc * 64 + n * 16 + lr;
#pragma unroll
      for (int r = 0; r < 4; ++r) {
        int rl = wr * 64 + m * 16 + g * 4 + r;
        int v = (acc[m][n][r] + 32) >> 6;
        v = v < -32768 ? -32768 : (v > 32767 ? 32767 : v);
        Tp[rl * 264 + cl] = (unsigned short)(short)v;
      }
    }
  __syncthreads();
  short* Pz = P16 + (size_t)z * 8192 * 256 + (size_t)m0 * 256;
#pragma unroll
  for (int pass = 0; pass < 8; ++pass) {
    int c = pass * 512 + tid;
    int r = c >> 5, off = (c & 31) * 8;
    s16x8 v = *(const s16x8*)(Tp + r * 264 + off);
    *(s16x8*)(Pz + (size_t)c * 8) = v;
  }
}

// ---------------- lnW2: fused reduce_ln + gemm6 ----------------
// Block owns 32 nodes: phase1 LN->slab (LDS); phase2 slab@W2 -> hq2/hq2n/colsum2.
__global__ __launch_bounds__(256) void lnW2(const short* __restrict__ P16,
                                            const char* __restrict__ hq1n,
                                            const int* __restrict__ colsum1,
                                            const float* __restrict__ dinv,
                                            const float* __restrict__ gamma,
                                            const float* __restrict__ beta,
                                            const float* __restrict__ W2,
                                            const float* __restrict__ b2,
                                            char* __restrict__ hq2,
                                            char* __restrict__ hq2n,
                                            int* __restrict__ colsum2) {
  __shared__ unsigned short smem[(256 + 32) * 264];  // Wt[256][264] | slab[32][264]
  __shared__ int colA[256];
  unsigned short* Wt = smem;
  unsigned short* slab = smem + 256 * 264;
  const int tid = threadIdx.x;
  const int n0 = blockIdx.x * 32;
  const int l = tid & 63;

  colA[tid] = 0;

  // phase 0: stage W2 -> Wt bf16, Wt[h'][h]
  for (int i = 0; i < 64; ++i) {
    int flat = (i * 256 + tid) * 4;
    f32x4 v = *(const f32x4*)(W2 + flat);
    int k = flat >> 8;
    int h0 = flat & 255;
#pragma unroll
    for (int j = 0; j < 4; ++j)
      Wt[(h0 + j) * 264 + k] = f2bf(v[j]);
  }

  // phase 1: LN rows n0..n0+31 -> slab (identical math to old reduce_ln)
  const size_t ZSTR = (size_t)8192 * 256;
  f32x4 gm = *(const f32x4*)(gamma + l * 4);
  f32x4 bt = *(const f32x4*)(beta + l * 4);
  i32x4 cs = *(const i32x4*)(colsum1 + l * 4);
  for (int it = 0; it < 8; ++it) {
    int row_l = it * 4 + (tid >> 6);
    int row = n0 + row_l;
    const short* p = P16 + (size_t)row * 256 + l * 4;
    s16x4 a = *(const s16x4*)p;
    s16x4 b = *(const s16x4*)(p + ZSTR);
    s16x4 c = *(const s16x4*)(p + 2 * ZSTR);
    s16x4 d = *(const s16x4*)(p + 3 * ZSTR);
    int q4 = *(const int*)(hq1n + (size_t)row * 256 + l * 4);
    float di = dinv[row];
    float gl[4];
    float s = 0.f, q = 0.f;
#pragma unroll
    for (int j = 0; j < 4; ++j) {
      float agg = (float)((int)a[j] + b[j] + c[j] + d[j]) * S16C +
                  0.5f * (float)cs[j] * INVSHS +
                  (float)((signed char)(q4 >> (8 * j))) * INVSHS;
      float v = agg * di;
      float gv = 0.5f * v * (1.0f + erff(v * 0.70710678118654752440f));
      gl[j] = gv;
      s += gv;
      q += gv * gv;
    }
#pragma unroll
    for (int off = 1; off < 64; off <<= 1) {
      s += __shfl_xor(s, off, 64);
      q += __shfl_xor(q, off, 64);
    }
    float mu = s * (1.0f / 256.0f);
    float var = q * (1.0f / 256.0f) - mu * mu;
    float rs = rsqrtf(fmaxf(var, 0.f) + 1e-6f);
#pragma unroll
    for (int j = 0; j < 4; ++j)
      slab[row_l * 264 + l * 4 + j] = f2bf((gl[j] - mu) * rs * gm[j] + bt[j]);
  }
  __syncthreads();

  // phase 2: D[h'=256][node=32] = Wt · slab^T  (bf16 MFMA)
  const int w = tid >> 6;
  const int g = l >> 4, lr = l & 15;
  f32x4 acc[4][2];
#pragma unroll
  for (int mf = 0; mf < 4; ++mf)
#pragma unroll
    for (int nf = 0; nf < 2; ++nf) {
      f32x4 z = {0.f, 0.f, 0.f, 0.f};
      acc[mf][nf] = z;
    }
#pragma unroll
  for (int ks = 0; ks < 8; ++ks) {
    s16x8 bq[2];
#pragma unroll
    for (int nf = 0; nf < 2; ++nf)
      bq[nf] = *(const s16x8*)(slab + (nf * 16 + lr) * 264 + ks * 32 + g * 8);
#pragma unroll
    for (int mf = 0; mf < 4; ++mf) {
      s16x8 aq = *(const s16x8*)(Wt + (w * 64 + mf * 16 + lr) * 264 + ks * 32 + g * 8);
#pragma unroll
      for (int nf = 0; nf < 2; ++nf)
        acc[mf][nf] = __builtin_amdgcn_mfma_f32_16x16x32_bf16(aq, bq[nf], acc[mf][nf],
                                                              0, 0, 0);
    }
  }
  __syncthreads();  // done reading Wt & slab; reuse space for outputs

  char* Tt = (char*)smem;            // [256 h'][48 node]
  char* T2 = (char*)smem + 12288;    // [32 node][272 h']
  float di2[2];
#pragma unroll
  for (int nf = 0; nf < 2; ++nf) di2[nf] = dinv[n0 + nf * 16 + lr];
#pragma unroll
  for (int mf = 0; mf < 4; ++mf)
#pragma unroll
    for (int r = 0; r < 4; ++r) {
      int hp = w * 64 + mf * 16 + g * 4 + r;
      float bias = b2[hp];
      int s2 = 0;
#pragma unroll
      for (int nf = 0; nf < 2; ++nf) {
        int node_l = nf * 16 + lr;
        int qv = q_hs((acc[mf][nf][r] + bias) * di2[nf]);
        Tt[hp * 48 + node_l] = (char)qv;
        T2[node_l * 272 + hp] = (char)qv;
        s2 += qv;
      }
      s2 += __shfl_xor(s2, 1, 64);
      s2 += __shfl_xor(s2, 2, 64);
      s2 += __shfl_xor(s2, 4, 64);
      s2 += __shfl_xor(s2, 8, 64);
      if (lr == 0) atomicAdd(&colA[hp], s2);
    }
  __syncthreads();
  {  // hq2 [h'][node]: thread = h'
    i32x4 v0 = *(const i32x4*)(Tt + tid * 48);
    i32x4 v1 = *(const i32x4*)(Tt + tid * 48 + 16);
    *(i32x4*)(hq2 + (size_t)tid * 8192 + n0) = v0;
    *(i32x4*)(hq2 + (size_t)tid * 8192 + n0 + 16) = v1;
  }
  {  // hq2n [node][h']
    int node = tid >> 3, ch = (tid & 7) * 32;
    i32x4 u0 = *(const i32x4*)(T2 + node * 272 + ch);
    i32x4 u1 = *(const i32x4*)(T2 + node * 272 + ch + 16);
    *(i32x4*)(hq2n + (size_t)(n0 + node) * 256 + ch) = u0;
    *(i32x4*)(hq2n + (size_t)(n0 + node) * 256 + ch + 16) = u1;
  }
  atomicAdd(&colsum2[tid], colA[tid]);
}

// ---------------- reduce2: out = dinv*(ΣP16*S16C + 0.5*cs2/2048 + hq2n/2048) ----------------
__global__ __launch_bounds__(256) void reduce_sc(const short* __restrict__ P16,
                                                 const char* __restrict__ hq2n,
                                                 const int* __restrict__ colsum2,
                                                 const float* __restrict__ dinv,
                                                 float* __restrict__ out) {
  const size_t ZSTR = (size_t)8192 * 256;
  int row = blockIdx.x * 4 + (threadIdx.x >> 6);
  int l = threadIdx.x & 63;
  const short* p = P16 + (size_t)row * 256 + l * 4;
  s16x4 a = *(const s16x4*)p;
  s16x4 b = *(const s16x4*)(p + ZSTR);
  s16x4 c = *(const s16x4*)(p + 2 * ZSTR);
  s16x4 d = *(const s16x4*)(p + 3 * ZSTR);
  int q4 = *(const int*)(hq2n + (size_t)row * 256 + l * 4);
  i32x4 cs = *(const i32x4*)(colsum2 + l * 4);
  float di = dinv[row];
  f32x4 o;
#pragma unroll
  for (int j = 0; j < 4; ++j) {
    float agg = (float)((int)a[j] + b[j] + c[j] + d[j]) * S16C +
                0.5f * (float)cs[j] * INVSHS +
                (float)((signed char)(q4 >> (8 * j))) * INVSHS;
    o[j] = agg * di;
  }
  *(f32x4*)(out + (size_t)row * 256 + l * 4) = o;
}

// ---------------- launch ----------------
extern "C" void kernel_launch(void* const* d_in, const int* in_sizes, int n_in,
                              void* d_out, int out_size, void* d_ws, size_t ws_size,
                              hipStream_t stream) {
  (void)in_sizes; (void)n_in; (void)out_size; (void)ws_size;
  const float* x     = (const float*)d_in[0];
  const float* adj   = (const float*)d_in[1];
  const float* W1    = (const float*)d_in[2];
  const float* b1    = (const float*)d_in[3];
  const float* W2    = (const float*)d_in[4];
  const float* b2    = (const float*)d_in[5];
  const float* gamma = (const float*)d_in[6];
  const float* beta  = (const float*)d_in[7];
  float* out = (float*)d_out;

  char* ws = (char*)d_ws;
  float* dinv          = (float*)ws;                           // 32 KB
  int* colsum1         = (int*)(ws + (32 << 10));              // 1 KB
  int* colsum2         = (int*)(ws + (36 << 10));              // 1 KB
  unsigned short* h1   = (unsigned short*)(ws + (1 << 20));    // 4 MB [256][8192] bf16
  char* hq1            = (char*)(ws + (8 << 20));              // 2 MB [256][8192] int8
  char* hq1n           = (char*)(ws + (10 << 20));             // 2 MB [8192][256] int8
  char* hq2            = (char*)(ws + (20 << 20));             // 2 MB [256][8192] int8
  char* hq2n           = (char*)(ws + (24 << 20));             // 2 MB [8192][256] int8
  short* P16           = (short*)(ws + (32 << 20));            // 16 MB [4][8192][256] i16
  char* adjq           = (char*)(ws + (64 << 20));             // 64 MB [8192][8192] int8

  // 1) gemm3 + adj->centered int8 + rowsum->dinv + colsum zero, fused
  prep<<<4352, 256, 0, stream>>>(adj, x, W1, b1, adjq, dinv, h1, colsum1, colsum2);
  // 2) hq1 both layouts + colsum1
  scale_tr<<<512, 256, 0, stream>>>(h1, dinv, hq1, hq1n, colsum1);
  // 3) P16 = partials of adjq_c @ hq1^T
  gemm_big<<<256, 512, 0, stream>>>(adjq, hq1, P16);
  // 4) fused LN + @W2 -> hq2/hq2n/colsum2
  lnW2<<<256, 256, 0, stream>>>(P16, hq1n, colsum1, dinv, gamma, beta, W2, b2,
                                hq2, hq2n, colsum2);
  // 5) P16 = partials of adjq_c @ hq2^T
  gemm_big<<<256, 512, 0, stream>>>(adjq, hq2, P16);
  // 6) out = dinv*(ΣP + 0.5*colsum2 + hs2)
  reduce_sc<<<2048, 256, 0, stream>>>(P16, hq2n, colsum2, dinv, out);
}

// Round 15
// 161.526 us; speedup vs baseline: 1.0874x; 1.0874x over previous
//
#include <hip/hip_runtime.h>
#include <math.h>

typedef __attribute__((ext_vector_type(4))) float f32x4;
typedef __attribute__((ext_vector_type(8))) short s16x8;
typedef __attribute__((ext_vector_type(4))) short s16x4;
typedef __attribute__((ext_vector_type(2))) int i32x2;
typedef __attribute__((ext_vector_type(4))) int i32x4;

// small-GEMM tile
#define BM 32
#define BN 256
#define BK 64
#define LDS_TILE ((BM + BN) * BK)

// big-GEMM tile (int8)
#define BM2 128
#define BN2 256
#define BK2 128              // elements = bytes per row-chunk
#define KFULL 8192
#define ZSPLIT 4
#define KQ (KFULL / ZSPLIT)  // 2048
#define ABYTES (BM2 * BK2)   // 16384
#define BBYTES (BN2 * BK2)   // 32768
#define BUFB (ABYTES + BBYTES)  // 49152 bytes per buffer

#define SHS 2048.0f
#define S16C (64.0f / (254.0f * 2048.0f))  // P16 units -> h-units (centered adj)
#define INVSHS (1.0f / 2048.0f)

__device__ __forceinline__ unsigned short f2bf(float f) {
  unsigned int u = __float_as_uint(f);
  u += 0x7fffu + ((u >> 16) & 1u);
  return (unsigned short)(u >> 16);
}
__device__ __forceinline__ float bf2f(unsigned short h) {
  unsigned int u = ((unsigned int)h) << 16;
  return __uint_as_float(u);
}
// round-to-nearest-even float->int for |x| < 2^22 (magic-add trick)
__device__ __forceinline__ int rne_i(float x) {
  return __float_as_int(x + 12582912.0f) - 0x4B400000;
}
__device__ __forceinline__ int q_hs(float v) {
  int q = rne_i(v * SHS);
  return q < -127 ? -127 : (q > 127 ? 127 : q);
}
__device__ __forceinline__ void gload16(const void* g, void* l) {
  __builtin_amdgcn_global_load_lds(
      (const __attribute__((address_space(1))) void*)g,
      (__attribute__((address_space(3))) void*)l, 16, 0, 0);
}

// ---------------- small GEMM (bf16 MFMA): C[M,N] = A[K,M]^T * BT[N,K]^T ----------------
// A read directly as [K][M] fp32 (weights, no pre-transpose).
// EPI 3: bf16 out = acc + bias[row]                      (gemm3 -> h1)
// EPI 6: int8 out [h][node] + int8 outn [node][h] + int colsum[h]  (gemm6)
template <bool BF32, int EPI>
__device__ __forceinline__ void gemm_small(int bx, unsigned short* ldsb,
                                           const float* __restrict__ A,
                                           const void* __restrict__ BTp,
                                           void* __restrict__ outp,
                                           char* __restrict__ outn,
                                           int* __restrict__ colsum,
                                           const float* __restrict__ bias,
                                           const float* __restrict__ dinv,
                                           int M, int N, int K) {
  const int tid = threadIdx.x;
  const int m0 = (bx & (M / BM - 1)) * BM;
  const int n0 = (bx / (M / BM)) * BN;
  const int sr = tid >> 3;
  const int sc = (tid & 7) * 8;
  const float* Bf = (const float*)BTp;
  const unsigned short* Bh = (const unsigned short*)BTp;

  float a_t[8];
  f32x4 b_f[8][2];
  s16x8 b_h[8];

  auto stage_load = [&](int k0) {
#pragma unroll
    for (int j = 0; j < 8; ++j)
      a_t[j] = A[(size_t)(k0 + sc + j) * M + m0 + sr];
#pragma unroll
    for (int it = 0; it < 8; ++it) {
      int n = n0 + it * 32 + sr;
      if (BF32) {
        const float* p = Bf + (size_t)n * K + k0 + sc;
        b_f[it][0] = *(const f32x4*)(p);
        b_f[it][1] = *(const f32x4*)(p + 4);
      } else {
        b_h[it] = *(const s16x8*)(Bh + (size_t)n * K + k0 + sc);
      }
    }
  };

  auto stage_write = [&](int buf) {
    unsigned short* L = ldsb + buf * LDS_TILE;
    {
      s16x8 v;
#pragma unroll
      for (int j = 0; j < 8; ++j) v[j] = (short)f2bf(a_t[j]);
      int idx = (sr * BK + sc) ^ ((sr & 7) << 3);
      *(s16x8*)(L + idx) = v;
    }
#pragma unroll
    for (int it = 0; it < 8; ++it) {
      int r = it * 32 + sr;
      s16x8 w;
      if (BF32) {
#pragma unroll
        for (int j = 0; j < 8; ++j)
          w[j] = (short)f2bf(j < 4 ? b_f[it][0][j] : b_f[it][1][j - 4]);
      } else {
        w = b_h[it];
      }
      int idx = BM * BK + ((r * BK + sc) ^ ((r & 7) << 3));
      *(s16x8*)(L + idx) = w;
    }
  };

  const int lane = tid & 63;
  const int wv = tid >> 6;
  const int g = lane >> 4, lr = lane & 15;

  int aidx[2][2], bidx[4][2];
#pragma unroll
  for (int m = 0; m < 2; ++m)
#pragma unroll
    for (int ks = 0; ks < 2; ++ks) {
      int r = m * 16 + lr;
      aidx[m][ks] = (r * BK + ks * 32 + g * 8) ^ ((r & 7) << 3);
    }
#pragma unroll
  for (int n = 0; n < 4; ++n)
#pragma unroll
    for (int ks = 0; ks < 2; ++ks) {
      int r = wv * 64 + n * 16 + lr;
      bidx[n][ks] = BM * BK + ((r * BK + ks * 32 + g * 8) ^ ((r & 7) << 3));
    }

  f32x4 acc[2][4];
#pragma unroll
  for (int m = 0; m < 2; ++m)
#pragma unroll
    for (int n = 0; n < 4; ++n) {
      f32x4 z = {0.f, 0.f, 0.f, 0.f};
      acc[m][n] = z;
    }

  auto compute = [&](int buf) {
    const unsigned short* L = ldsb + buf * LDS_TILE;
    s16x8 af[2][2], bfr[4][2];
#pragma unroll
    for (int m = 0; m < 2; ++m)
#pragma unroll
      for (int ks = 0; ks < 2; ++ks) af[m][ks] = *(const s16x8*)(L + aidx[m][ks]);
#pragma unroll
    for (int n = 0; n < 4; ++n)
#pragma unroll
      for (int ks = 0; ks < 2; ++ks) bfr[n][ks] = *(const s16x8*)(L + bidx[n][ks]);
#pragma unroll
    for (int m = 0; m < 2; ++m)
#pragma unroll
      for (int n = 0; n < 4; ++n)
#pragma unroll
        for (int ks = 0; ks < 2; ++ks)
          acc[m][n] = __builtin_amdgcn_mfma_f32_16x16x32_bf16(af[m][ks], bfr[n][ks],
                                                              acc[m][n], 0, 0, 0);
  };

  stage_load(0);
  stage_write(0);
  __syncthreads();
  int cur = 0;
  const int nt = K / BK;
  for (int t = 0; t < nt; ++t) {
    if (t + 1 < nt) stage_load((t + 1) * BK);
    compute(cur);
    if (t + 1 < nt) {
      stage_write(cur ^ 1);
      __syncthreads();
      cur ^= 1;
    }
  }

  if constexpr (EPI == 3) {
#pragma unroll
    for (int m = 0; m < 2; ++m)
#pragma unroll
      for (int n = 0; n < 4; ++n) {
        int col = n0 + wv * 64 + n * 16 + lr;
#pragma unroll
        for (int r = 0; r < 4; ++r) {
          int row = m0 + m * 16 + g * 4 + r;
          ((unsigned short*)outp)[(size_t)row * N + col] = f2bf(acc[m][n][r] + bias[row]);
        }
      }
  } else {
    // EPI 6: quantize; [h][node] scalar + [node][h] via LDS T2[256][48] + colsum
    __syncthreads();
    char* T2 = (char*)ldsb;
    int* colA2 = (int*)((char*)ldsb + 16384);
    if (tid < 32) colA2[tid] = 0;
    __syncthreads();
    int prl[2][4];
#pragma unroll
    for (int m = 0; m < 2; ++m)
#pragma unroll
      for (int r = 0; r < 4; ++r) prl[m][r] = 0;
#pragma unroll
    for (int m = 0; m < 2; ++m)
#pragma unroll
      for (int n = 0; n < 4; ++n) {
        int cl = wv * 64 + n * 16 + lr;
        float dv = dinv[n0 + cl];
#pragma unroll
        for (int r = 0; r < 4; ++r) {
          int rl = m * 16 + g * 4 + r;
          int q = q_hs((acc[m][n][r] + bias[m0 + rl]) * dv);
          T2[cl * 48 + rl] = (char)q;
          ((char*)outp)[(size_t)(m0 + rl) * N + n0 + cl] = (char)q;
          prl[m][r] += q;
        }
      }
#pragma unroll
    for (int m = 0; m < 2; ++m)
#pragma unroll
      for (int r = 0; r < 4; ++r)
        atomicAdd(&colA2[m * 16 + g * 4 + r], prl[m][r]);
    __syncthreads();
#pragma unroll
    for (int h = 0; h < 2; ++h) {
      i32x4 vv = *(const i32x4*)(T2 + tid * 48 + h * 16);
      *(i32x4*)(outn + (size_t)(n0 + tid) * 256 + m0 + h * 16) = vv;
    }
    if (tid < 32) atomicAdd(&colsum[m0 + tid], colA2[tid]);
  }
}

// ---------------- prep: gemm3 blocks [0,256) + adj conv/rowsum blocks [256,4352) ----------------
__global__ __launch_bounds__(256) void prep(const float* __restrict__ adj,
                                            const float* __restrict__ x,
                                            const float* __restrict__ W1,
                                            const float* __restrict__ b1,
                                            char* __restrict__ adjq,
                                            float* __restrict__ dinv,
                                            unsigned short* __restrict__ h1,
                                            int* __restrict__ colsum1,
                                            int* __restrict__ colsum2) {
  __shared__ unsigned short lds[2 * LDS_TILE];
  int bx = blockIdx.x;
  if (bx < 256) {
    gemm_small<true, 3>(bx, lds, W1, x, h1, nullptr, nullptr, b1, nullptr, 256, 8192, 512);
    return;
  }
  bx -= 256;
  const int tid = threadIdx.x;
  if (bx == 0) {  // zero colsum accumulators (used by later launches)
    colsum1[tid] = 0;
    colsum2[tid] = 0;
  }
  float* smf = (float*)lds;
  float psum[2];
#pragma unroll
  for (int rr = 0; rr < 2; ++rr) {
    int row = bx * 2 + rr;
    const float* src = adj + (size_t)row * 8192;
    char* dst = adjq + (size_t)row * 8192;
    float s = 0.f;
    for (int c = tid * 8; c < 8192; c += 2048) {
      f32x4 v0 = __builtin_nontemporal_load((const f32x4*)(src + c));
      f32x4 v1 = __builtin_nontemporal_load((const f32x4*)(src + c + 4));
      s += v0[0] + v0[1] + v0[2] + v0[3] + v1[0] + v1[1] + v1[2] + v1[3];
      // centered quantization: adj ≈ 0.5 + adjq/254 (mean handled via colsum terms)
      i32x2 o;
      o[0] = (rne_i((v0[0] - 0.5f) * 254.f) & 0xff) |
             ((rne_i((v0[1] - 0.5f) * 254.f) & 0xff) << 8) |
             ((rne_i((v0[2] - 0.5f) * 254.f) & 0xff) << 16) |
             (rne_i((v0[3] - 0.5f) * 254.f) << 24);
      o[1] = (rne_i((v1[0] - 0.5f) * 254.f) & 0xff) |
             ((rne_i((v1[1] - 0.5f) * 254.f) & 0xff) << 8) |
             ((rne_i((v1[2] - 0.5f) * 254.f) & 0xff) << 16) |
             (rne_i((v1[3] - 0.5f) * 254.f) << 24);
      *(i32x2*)(dst + c) = o;
    }
    psum[rr] = s;
  }
#pragma unroll
  for (int rr = 0; rr < 2; ++rr) {
    float s = psum[rr];
#pragma unroll
    for (int off = 32; off > 0; off >>= 1) s += __shfl_down(s, off, 64);
    if ((tid & 63) == 0) smf[rr * 4 + (tid >> 6)] = s;
  }
  __syncthreads();
  if (tid < 2) {
    float tot = smf[tid * 4] + smf[tid * 4 + 1] + smf[tid * 4 + 2] + smf[tid * 4 + 3];
    dinv[bx * 2 + tid] = rsqrtf(tot + 1.0f);
  }
}

// ---------------- scale_tr: hq1[h][k]=q(h1*dinv[k]) + hq1n[k][h] + colsum1 ----------------
__global__ __launch_bounds__(256) void scale_tr(const unsigned short* __restrict__ h1,
                                                const float* __restrict__ dinv,
                                                char* __restrict__ hq1,
                                                char* __restrict__ hq1n,
                                                int* __restrict__ colsum1) {
  __shared__ char Tq[64][80];  // [node_local][h_local pad]
  __shared__ int colA[64];
  int nt_ = blockIdx.x >> 2, ht = blockIdx.x & 3;
  int n0 = nt_ * 64, h0 = ht * 64;
  const int tid = threadIdx.x;
  const int c8 = (tid & 7) * 8;
  if (tid < 64) colA[tid] = 0;
  __syncthreads();
  f32x4 d0 = *(const f32x4*)(dinv + n0 + c8);
  f32x4 d1 = *(const f32x4*)(dinv + n0 + c8 + 4);
#pragma unroll
  for (int it = 0; it < 2; ++it) {
    int hh = (tid >> 3) + it * 32;
    s16x8 v = *(const s16x8*)(h1 + (size_t)(h0 + hh) * 8192 + n0 + c8);
    unsigned int lo = 0, hi = 0;
    int ssum = 0;
#pragma unroll
    for (int j = 0; j < 8; ++j) {
      float dv = (j < 4) ? d0[j] : d1[j - 4];
      int q = q_hs(bf2f((unsigned short)v[j]) * dv);
      Tq[c8 + j][hh] = (char)q;
      ssum += q;
      if (j < 4) lo |= ((unsigned int)(q & 0xff)) << (8 * j);
      else       hi |= ((unsigned int)(q & 0xff)) << (8 * (j - 4));
    }
    i32x2 o;
    o[0] = (int)lo;
    o[1] = (int)hi;
    *(i32x2*)(hq1 + (size_t)(h0 + hh) * 8192 + n0 + c8) = o;
    ssum += __shfl_xor(ssum, 1, 64);
    ssum += __shfl_xor(ssum, 2, 64);
    ssum += __shfl_xor(ssum, 4, 64);
    if ((tid & 7) == 0) atomicAdd(&colA[hh], ssum);
  }
  __syncthreads();
  int node = tid >> 2, h16 = (tid & 3) * 16;
  i32x4 vv = *(const i32x4*)(&Tq[node][h16]);
  *(i32x4*)(hq1n + (size_t)(n0 + node) * 256 + h0 + h16) = vv;
  if (tid < 64) atomicAdd(&colsum1[h0 + tid], colA[tid]);
}

// ---------------- big GEMM int8 (split-K=4): P16[z] = (adjq_c @ Bq^T + 32) >> 6 ----------------
// Centered adj -> zero-mean partials -> int16 safe for BOTH layers.
__global__ __launch_bounds__(512) void gemm_big(const char* __restrict__ A,
                                                const char* __restrict__ B,
                                                short* __restrict__ P16) {
  __shared__ char lds[3 * BUFB];  // 144 KB
  const int tid = threadIdx.x;
  const int mt = blockIdx.x & 63;
  const int z = blockIdx.x >> 6;
  const int m0 = mt * BM2;

  const int trow = tid >> 3;          // 0..63
  const int srcgr = (tid & 7) ^ (trow & 7);

  const char* Asrc[2];
#pragma unroll
  for (int j = 0; j < 2; ++j)
    Asrc[j] = A + (size_t)(m0 + j * 64 + trow) * KFULL + (size_t)z * KQ + srcgr * 16;
  const char* Bsrc[4];
#pragma unroll
  for (int j = 0; j < 4; ++j)
    Bsrc[j] = B + (size_t)(j * 64 + trow) * KFULL + (size_t)z * KQ + srcgr * 16;

  auto stage = [&](int buf, int t) {  // 6 gload16/thread
    char* L = lds + buf * BUFB;
#pragma unroll
    for (int j = 0; j < 2; ++j)
      gload16(Asrc[j] + (size_t)t * BK2, L + (j * 512 + tid) * 16);
#pragma unroll
    for (int j = 0; j < 4; ++j)
      gload16(Bsrc[j] + (size_t)t * BK2, L + ABYTES + (j * 512 + tid) * 16);
  };

  const int w = tid >> 6, l = tid & 63;
  const int wr = w >> 2, wc = w & 3;
  const int g = l >> 4, lr = l & 15;
  int aoff[4][2], boff[4][2];
#pragma unroll
  for (int m = 0; m < 4; ++m)
#pragma unroll
    for (int ks = 0; ks < 2; ++ks) {
      int r = wr * 64 + m * 16 + lr;
      aoff[m][ks] = r * BK2 + (((ks * 4 + g) ^ (r & 7)) * 16);
    }
#pragma unroll
  for (int n = 0; n < 4; ++n)
#pragma unroll
    for (int ks = 0; ks < 2; ++ks) {
      int r = wc * 64 + n * 16 + lr;
      boff[n][ks] = ABYTES + r * BK2 + (((ks * 4 + g) ^ (r & 7)) * 16);
    }

  i32x4 acc[4][4];
#pragma unroll
  for (int m = 0; m < 4; ++m)
#pragma unroll
    for (int n = 0; n < 4; ++n) {
      i32x4 zz = {0, 0, 0, 0};
      acc[m][n] = zz;
    }

  stage(0, 0);
  stage(1, 1);

  const int nt = KQ / BK2;  // 16
  for (int t = 0; t < nt; ++t) {
    int cur = t % 3;
    if (t + 1 < nt) asm volatile("s_waitcnt vmcnt(6)" ::: "memory");
    else            asm volatile("s_waitcnt vmcnt(0)" ::: "memory");
    asm volatile("s_barrier" ::: "memory");
    __builtin_amdgcn_sched_barrier(0);

    const char* L = lds + cur * BUFB;
    i32x4 af[4][2], bfr[4][2];
#pragma unroll
    for (int m = 0; m < 4; ++m)
#pragma unroll
      for (int ks = 0; ks < 2; ++ks) af[m][ks] = *(const i32x4*)(L + aoff[m][ks]);
#pragma unroll
    for (int n = 0; n < 4; ++n)
#pragma unroll
      for (int ks = 0; ks < 2; ++ks) bfr[n][ks] = *(const i32x4*)(L + boff[n][ks]);

    if (t + 2 < nt) stage((t + 2) % 3, t + 2);

    __builtin_amdgcn_s_setprio(1);
#pragma unroll
    for (int m = 0; m < 4; ++m)
#pragma unroll
      for (int n = 0; n < 4; ++n)
#pragma unroll
        for (int ks = 0; ks < 2; ++ks)
          acc[m][n] = __builtin_amdgcn_mfma_i32_16x16x64_i8(af[m][ks], bfr[n][ks],
                                                            acc[m][n], 0, 0, 0);
    __builtin_amdgcn_s_setprio(0);
  }

  // epilogue: int16 partials via LDS transpose [128][264], coalesced 16B stores
  __syncthreads();
  unsigned short* Tp = (unsigned short*)lds;
#pragma unroll
  for (int m = 0; m < 4; ++m)
#pragma unroll
    for (int n = 0; n < 4; ++n) {
      int cl = wc * 64 + n * 16 + lr;
#pragma unroll
      for (int r = 0; r < 4; ++r) {
        int rl = wr * 64 + m * 16 + g * 4 + r;
        int v = (acc[m][n][r] + 32) >> 6;
        v = v < -32768 ? -32768 : (v > 32767 ? 32767 : v);
        Tp[rl * 264 + cl] = (unsigned short)(short)v;
      }
    }
  __syncthreads();
  short* Pz = P16 + (size_t)z * 8192 * 256 + (size_t)m0 * 256;
#pragma unroll
  for (int pass = 0; pass < 8; ++pass) {
    int c = pass * 512 + tid;            // 16B chunk id
    int r = c >> 5, off = (c & 31) * 8;  // in shorts
    s16x8 v = *(const s16x8*)(Tp + r * 264 + off);
    *(s16x8*)(Pz + (size_t)c * 8) = v;
  }
}

// ---------------- reduce1: hln = LN(GELU(dinv*(ΣP16*S16C + 0.5*cs1/2048 + hq1n/2048))) ----------------
__global__ __launch_bounds__(256) void reduce_ln(const short* __restrict__ P16,
                                                 const char* __restrict__ hq1n,
                                                 const int* __restrict__ colsum1,
                                                 const float* __restrict__ dinv,
                                                 const float* __restrict__ gamma,
                                                 const float* __restrict__ beta,
                                                 unsigned short* __restrict__ hln) {
  const size_t ZSTR = (size_t)8192 * 256;
  int row = blockIdx.x * 4 + (threadIdx.x >> 6);
  int l = threadIdx.x & 63;
  const short* p = P16 + (size_t)row * 256 + l * 4;
  s16x4 a = *(const s16x4*)p;
  s16x4 b = *(const s16x4*)(p + ZSTR);
  s16x4 c = *(const s16x4*)(p + 2 * ZSTR);
  s16x4 d = *(const s16x4*)(p + 3 * ZSTR);
  int q4 = *(const int*)(hq1n + (size_t)row * 256 + l * 4);
  i32x4 cs = *(const i32x4*)(colsum1 + l * 4);
  float di = dinv[row];
  float gl[4];
  float s = 0.f, q = 0.f;
#pragma unroll
  for (int j = 0; j < 4; ++j) {
    float agg = (float)((int)a[j] + b[j] + c[j] + d[j]) * S16C +
                0.5f * (float)cs[j] * INVSHS +
                (float)((signed char)(q4 >> (8 * j))) * INVSHS;
    float v = agg * di;
    float gv = 0.5f * v * (1.0f + erff(v * 0.70710678118654752440f));
    gl[j] = gv;
    s += gv;
    q += gv * gv;
  }
#pragma unroll
  for (int off = 1; off < 64; off <<= 1) {
    s += __shfl_xor(s, off, 64);
    q += __shfl_xor(q, off, 64);
  }
  float mu = s * (1.0f / 256.0f);
  float var = q * (1.0f / 256.0f) - mu * mu;
  float rs = rsqrtf(fmaxf(var, 0.f) + 1e-6f);
  f32x4 gm = *(const f32x4*)(gamma + l * 4);
  f32x4 bt = *(const f32x4*)(beta + l * 4);
  unsigned short o4[4];
#pragma unroll
  for (int j = 0; j < 4; ++j)
    o4[j] = f2bf((gl[j] - mu) * rs * gm[j] + bt[j]);
  *(unsigned long long*)(hln + (size_t)row * 256 + l * 4) =
      *(const unsigned long long*)o4;
}

// ---------------- reduce2: out = dinv*(ΣP16*S16C + 0.5*cs2/2048 + hq2n/2048) ----------------
__global__ __launch_bounds__(256) void reduce_sc(const short* __restrict__ P16,
                                                 const char* __restrict__ hq2n,
                                                 const int* __restrict__ colsum2,
                                                 const float* __restrict__ dinv,
                                                 float* __restrict__ out) {
  const size_t ZSTR = (size_t)8192 * 256;
  int row = blockIdx.x * 4 + (threadIdx.x >> 6);
  int l = threadIdx.x & 63;
  const short* p = P16 + (size_t)row * 256 + l * 4;
  s16x4 a = *(const s16x4*)p;
  s16x4 b = *(const s16x4*)(p + ZSTR);
  s16x4 c = *(const s16x4*)(p + 2 * ZSTR);
  s16x4 d = *(const s16x4*)(p + 3 * ZSTR);
  int q4 = *(const int*)(hq2n + (size_t)row * 256 + l * 4);
  i32x4 cs = *(const i32x4*)(colsum2 + l * 4);
  float di = dinv[row];
  f32x4 o;
#pragma unroll
  for (int j = 0; j < 4; ++j) {
    float agg = (float)((int)a[j] + b[j] + c[j] + d[j]) * S16C +
                0.5f * (float)cs[j] * INVSHS +
                (float)((signed char)(q4 >> (8 * j))) * INVSHS;
    o[j] = agg * di;
  }
  *(f32x4*)(out + (size_t)row * 256 + l * 4) = o;
}

// ---------------- GEMM6: hq2 [h][node] + hq2n [node][h] + colsum2 ----------------
__global__ __launch_bounds__(256) void gemm6_k(const float* __restrict__ W2,
                                               const unsigned short* __restrict__ hln,
                                               char* __restrict__ hq2,
                                               char* __restrict__ hq2n,
                                               int* __restrict__ colsum2,
                                               const float* __restrict__ b2,
                                               const float* __restrict__ dinv) {
  __shared__ unsigned short lds[2 * LDS_TILE];
  gemm_small<false, 6>(blockIdx.x, lds, W2, hln, hq2, hq2n, colsum2, b2, dinv,
                       256, 8192, 256);
}

// ---------------- launch ----------------
extern "C" void kernel_launch(void* const* d_in, const int* in_sizes, int n_in,
                              void* d_out, int out_size, void* d_ws, size_t ws_size,
                              hipStream_t stream) {
  (void)in_sizes; (void)n_in; (void)out_size; (void)ws_size;
  const float* x     = (const float*)d_in[0];
  const float* adj   = (const float*)d_in[1];
  const float* W1    = (const float*)d_in[2];
  const float* b1    = (const float*)d_in[3];
  const float* W2    = (const float*)d_in[4];
  const float* b2    = (const float*)d_in[5];
  const float* gamma = (const float*)d_in[6];
  const float* beta  = (const float*)d_in[7];
  float* out = (float*)d_out;

  char* ws = (char*)d_ws;
  float* dinv          = (float*)ws;                           // 32 KB
  int* colsum1         = (int*)(ws + (32 << 10));              // 1 KB
  int* colsum2         = (int*)(ws + (36 << 10));              // 1 KB
  unsigned short* h1   = (unsigned short*)(ws + (1 << 20));    // 4 MB [256][8192] bf16
  char* hq1            = (char*)(ws + (8 << 20));              // 2 MB [256][8192] int8
  char* hq1n           = (char*)(ws + (10 << 20));             // 2 MB [8192][256] int8
  unsigned short* hln  = (unsigned short*)(ws + (14 << 20));   // 4 MB [8192][256] bf16
  char* hq2            = (char*)(ws + (20 << 20));             // 2 MB [256][8192] int8
  char* hq2n           = (char*)(ws + (24 << 20));             // 2 MB [8192][256] int8
  short* P16           = (short*)(ws + (32 << 20));            // 16 MB [4][8192][256] i16
  char* adjq           = (char*)(ws + (64 << 20));             // 64 MB [8192][8192] int8 (centered)

  // 1) gemm3 (h1 bf16) + adj->centered int8 + rowsum->dinv + colsum zero, fused
  prep<<<4352, 256, 0, stream>>>(adj, x, W1, b1, adjq, dinv, h1, colsum1, colsum2);
  // 2) hq1 = int8(h1 * dinv * 2048), both layouts + colsum1
  scale_tr<<<512, 256, 0, stream>>>(h1, dinv, hq1, hq1n, colsum1);
  // 3) P16 = split-K=4 int16 partials of adjq_c @ hq1^T
  gemm_big<<<256, 512, 0, stream>>>(adjq, hq1, P16);
  // 4) hln = LN(GELU(dinv*(ΣP + 0.5*colsum1 + hs1)))
  reduce_ln<<<2048, 256, 0, stream>>>(P16, hq1n, colsum1, dinv, gamma, beta, hln);
  // 5) hq2 = int8((hln @ W2 + b2)^T * dinv * 2048), both layouts + colsum2
  gemm6_k<<<256, 256, 0, stream>>>(W2, hln, hq2, hq2n, colsum2, b2, dinv);
  // 6) P16 = split-K=4 int16 partials of adjq_c @ hq2^T
  gemm_big<<<256, 512, 0, stream>>>(adjq, hq2, P16);
  // 7) out = dinv*(ΣP + 0.5*colsum2 + hs2)
  reduce_sc<<<2048, 256, 0, stream>>>(P16, hq2n, colsum2, dinv, out);
}